// Round 19
// baseline (73.353 us; speedup 1.0000x reference)
//
#include <hip/hip_runtime.h>

// Anti-causal attention (key s valid iff s > l), scale=1/8 after masking.
// Row L-1 fully masked -> softmax uniform -> out = mean(V).
// B=2, L=S=2048, H=16, E=D=64, fp32 in/out, bf16 MFMA compute.
// v19: v17 (fixed-max softmax, verified 61.2us) + key-range split-S for heavy
//      tiles: fixed-max partials are ADDITIVE (no max merge), key halves are
//      disjoint (no staging duplication). yi<8 -> 2 blocks (<=8 rounds each),
//      yi>=8 unsplit. Split blocks write f32 num/den partials to ws; merge
//      kernel combines. Falls back to verified v17 if ws too small.

#define B_ 2
#define L_ 2048
#define H_ 16
#define E_ 64
#define S_ 2048
#define D_ 64
#define NR_ 16              /* S/128 rounds */
#define CSH 16.0f           /* fixed exp2 shift (integer => exact) */
#define QSCALE 0.18033688011112042f /* 0.125 * log2(e) */

typedef __attribute__((ext_vector_type(4))) float f32x4;
typedef __attribute__((ext_vector_type(16))) float f32x16;
typedef __attribute__((ext_vector_type(8))) short short8;
typedef __attribute__((ext_vector_type(2))) unsigned int uint2v;
typedef __attribute__((ext_vector_type(4))) unsigned int uint4v;
typedef unsigned short ushort;

__device__ __forceinline__ unsigned short f2bf(float f) {
  unsigned int u = __builtin_bit_cast(unsigned int, f);
  u = (u + 0x7FFFu + ((u >> 16) & 1u)) >> 16;  // RNE
  return (unsigned short)u;
}
__device__ __forceinline__ unsigned int pkbf(float a, float b) {
  return (unsigned int)f2bf(a) | ((unsigned int)f2bf(b) << 16);
}
__device__ __forceinline__ unsigned cvtpk(float a, float b) {
  unsigned r;
  asm("v_cvt_pk_bf16_f32 %0, %1, %2" : "=v"(r) : "v"(a), "v"(b));
  return r;
}
__device__ __forceinline__ uint2v plswap(unsigned a, unsigned b, int hi) {
#if __has_builtin(__builtin_amdgcn_permlane32_swap)
  (void)hi;
  return __builtin_amdgcn_permlane32_swap(a, b, false, false);
#else
  unsigned ax = (unsigned)__shfl_xor((int)a, 32);
  unsigned bx = (unsigned)__shfl_xor((int)b, 32);
  uint2v r;
  r[0] = hi ? bx : a;
  r[1] = hi ? b : ax;
  return r;
#endif
}
__device__ __forceinline__ f32x16 zero16() {
  f32x16 z;
#pragma unroll
  for (int i = 0; i < 16; ++i) z[i] = 0.f;
  return z;
}

// -------- fused prep (R15-verified) + V partial-means --------
__global__ __launch_bounds__(256) void prep_all(const float* __restrict__ Kg,
                                                const float* __restrict__ Vg,
                                                ushort* __restrict__ Kb,
                                                ushort* __restrict__ Vt,
                                                float* __restrict__ part) {
  __shared__ ushort Tl[64][72];
  const int blk = (int)blockIdx.x;
  const int tid = (int)threadIdx.x;
  if (blk < 2048) {  // K path (R10-verified)
    const int t = blk * 256 + tid;
    const int orow = t >> 3, e0 = (t & 7) << 3;
    const int s = orow & (S_ - 1), bh = orow >> 11;
    const int b = bh >> 4, h = bh & 15;
    const float* src = Kg + ((size_t)((b * S_ + s) * H_ + h)) * E_ + e0;
    f32x4 a = ((const f32x4*)src)[0], c = ((const f32x4*)src)[1];
    short8 o;
    o[0]=(short)f2bf(a[0]); o[1]=(short)f2bf(a[1]); o[2]=(short)f2bf(a[2]); o[3]=(short)f2bf(a[3]);
    o[4]=(short)f2bf(c[0]); o[5]=(short)f2bf(c[1]); o[6]=(short)f2bf(c[2]); o[7]=(short)f2bf(c[3]);
    *(short8*)(Kb + (size_t)orow * E_ + e0) = o;
  } else {  // V path (R10-verified) + partial means (R15-verified)
    const int vb = blk - 2048;
    const int bh = vb & 31, st = vb >> 5;
    const int b = bh >> 4, h = bh & 15;
    const int s0 = st << 6;
    {
      const int sr = tid >> 2, d0 = (tid & 3) << 4;
      const float* src = Vg + ((size_t)((b * S_ + s0 + sr) * H_ + h)) * D_ + d0;
      f32x4 v0 = ((const f32x4*)src)[0], v1 = ((const f32x4*)src)[1];
      f32x4 v2 = ((const f32x4*)src)[2], v3 = ((const f32x4*)src)[3];
      ushort* dst = &Tl[sr][d0];
      dst[0]=f2bf(v0[0]); dst[1]=f2bf(v0[1]); dst[2]=f2bf(v0[2]); dst[3]=f2bf(v0[3]);
      dst[4]=f2bf(v1[0]); dst[5]=f2bf(v1[1]); dst[6]=f2bf(v1[2]); dst[7]=f2bf(v1[3]);
      dst[8]=f2bf(v2[0]); dst[9]=f2bf(v2[1]); dst[10]=f2bf(v2[2]); dst[11]=f2bf(v2[3]);
      dst[12]=f2bf(v3[0]); dst[13]=f2bf(v3[1]); dst[14]=f2bf(v3[2]); dst[15]=f2bf(v3[3]);
    }
    __syncthreads();
    {
      const int d = tid >> 2, sb = (tid & 3) << 4;
      short8 o0, o1;
#pragma unroll
      for (int j = 0; j < 8; ++j) {
        o0[j] = (short)Tl[sb + j][d];
        o1[j] = (short)Tl[sb + 8 + j][d];
      }
      ushort* dst = Vt + ((size_t)bh * D_ + d) * S_ + s0 + sb;
      *(short8*)dst = o0;
      *(short8*)(dst + 8) = o1;
    }
    if (tid < 64) {
      float sum = 0.f;
#pragma unroll 8
      for (int s = 0; s < 64; ++s)
        sum += __builtin_bit_cast(float, (unsigned)Tl[s][tid] << 16);
      part[(size_t)(bh * 32 + st) * 64 + tid] = sum;
    }
  }
}

// ---------------- staging (v9-verified, verbatim): 128-key image ----------------
struct Stage8 { short8 k[4]; short8 v[4]; };

__device__ __forceinline__ Stage8 sload(const ushort* __restrict__ Kbh,
                                        const ushort* __restrict__ VbhT,
                                        int s0, int tid) {
  Stage8 r;
  const int sl = tid >> 1, gb = (tid & 1) * 4;
  const ushort* kp = Kbh + (size_t)(s0 + sl) * E_ + gb * 8;
  r.k[0] = *(const short8*)(kp);
  r.k[1] = *(const short8*)(kp + 8);
  r.k[2] = *(const short8*)(kp + 16);
  r.k[3] = *(const short8*)(kp + 24);
  const int d = tid >> 2, sb = (tid & 3) * 32;
  const ushort* vp = VbhT + (size_t)d * S_ + s0 + sb;
  r.v[0] = *(const short8*)(vp);
  r.v[1] = *(const short8*)(vp + 8);
  r.v[2] = *(const short8*)(vp + 16);
  r.v[3] = *(const short8*)(vp + 24);
  return r;
}

__device__ __forceinline__ void swrite(ushort* SM, const Stage8& r, int tid) {
  const int sl = tid >> 1, gb = (tid & 1) * 4;
#pragma unroll
  for (int j = 0; j < 4; ++j)
    *(short8*)(SM + sl * 64 + (((gb + j) ^ (sl & 7)) << 3)) = r.k[j];
  const int d = tid >> 2, sgb = (tid & 3) * 4;
#pragma unroll
  for (int j = 0; j < 4; ++j) {
    const int sgg = sgb + j;
    *(short8*)(SM + 8192 + (sgg >> 3) * 4096 + d * 64 + (((sgg & 7) ^ (d & 7)) << 3)) = r.v[j];
  }
}

// ---------------- shared tile body (v17-verified compute, fixed-max softmax) ------
// Processes rounds [rs, re) for 128 q-rows at q0 of head bh. Returns acc/dsum.
__device__ __forceinline__ void tile_body(
    const float* __restrict__ Qg, const ushort* __restrict__ Kb,
    const ushort* __restrict__ Vt, ushort* SM0, ushort* SM1,
    int b, int h, int bh, int q0, int rs, int re, int tid,
    f32x16& acc0, f32x16& acc1, float& dsum, int& qbase_o, int& qrow_o) {
  const int w = tid >> 6, lane = tid & 63;
  const int hi = lane >> 5, c32 = lane & 31;
  const int qbase = q0 + (w << 5);
  const int qrow = qbase + c32;
  qbase_o = qbase; qrow_o = qrow;

  const ushort* Kbh = Kb + (size_t)bh * (S_ * E_);
  const ushort* VbhT = Vt + (size_t)bh * (D_ * S_);

  short8 qf[4];
  {
    const float* qr = Qg + ((size_t)((b * L_ + qrow) * H_ + h)) * E_;
#pragma unroll
    for (int kc = 0; kc < 4; ++kc) {
      f32x4 x = *(const f32x4*)(qr + kc * 16 + hi * 8);
      f32x4 y = *(const f32x4*)(qr + kc * 16 + hi * 8 + 4);
      short8 q;
      q[0]=(short)f2bf(QSCALE*x[0]); q[1]=(short)f2bf(QSCALE*x[1]);
      q[2]=(short)f2bf(QSCALE*x[2]); q[3]=(short)f2bf(QSCALE*x[3]);
      q[4]=(short)f2bf(QSCALE*y[0]); q[5]=(short)f2bf(QSCALE*y[1]);
      q[6]=(short)f2bf(QSCALE*y[2]); q[7]=(short)f2bf(QSCALE*y[3]);
      qf[kc] = q;
    }
  }

  acc0 = zero16(); acc1 = zero16(); dsum = 0.f;

  {
    Stage8 s = sload(Kbh, VbhT, rs << 7, tid);
    swrite(SM0, s, tid);
  }
  __syncthreads();

  for (int r = rs; r < re; ++r) {
    ushort* SMc = ((r - rs) & 1) ? SM1 : SM0;
    ushort* SMn = ((r - rs) & 1) ? SM0 : SM1;
    const bool more = (r + 1) < re;
    Stage8 nxt;
    if (more) nxt = sload(Kbh, VbhT, (r + 1) << 7, tid);  // issue early (T14)

    const ushort* img = SMc;
#pragma unroll
    for (int half = 0; half < 2; ++half) {
      const int s0 = (r << 7) + (half << 6);
      if (s0 + 63 > qbase) {
        f32x16 st0 = zero16(), st1 = zero16();
        __builtin_amdgcn_s_setprio(1);
#pragma unroll
        for (int kc = 0; kc < 4; ++kc) {
          const int gg = 2 * kc + hi;
          const int rl0 = (half << 6) + c32, rl1 = rl0 + 32;
          short8 k0 = *(const short8*)(img + rl0 * 64 + ((gg ^ (rl0 & 7)) << 3));
          short8 k1 = *(const short8*)(img + rl1 * 64 + ((gg ^ (rl1 & 7)) << 3));
          st0 = __builtin_amdgcn_mfma_f32_32x32x16_bf16(k0, qf[kc], st0, 0, 0, 0);
          st1 = __builtin_amdgcn_mfma_f32_32x32x16_bf16(k1, qf[kc], st1, 0, 0, 0);
        }
        __builtin_amdgcn_s_setprio(0);

        if (s0 < qbase + 32) {
#pragma unroll
          for (int r16 = 0; r16 < 16; ++r16) {
            const int ko = (r16 & 3) + 8 * (r16 >> 2) + 4 * hi;
            st0[r16] = (s0 + ko <= qrow) ? -1e30f : st0[r16];
            st1[r16] = (s0 + 32 + ko <= qrow) ? -1e30f : st1[r16];
          }
        }

        float ps = 0.f;
#pragma unroll
        for (int r16 = 0; r16 < 16; ++r16) { st0[r16] = exp2f(st0[r16] - CSH); ps += st0[r16]; }
#pragma unroll
        for (int r16 = 0; r16 < 16; ++r16) { st1[r16] = exp2f(st1[r16] - CSH); ps += st1[r16]; }
        dsum += ps;

        short8 pf[4];
#pragma unroll
        for (int kp = 0; kp < 4; ++kp) {
          const f32x16 stt = (kp < 2) ? st0 : st1;
          const int u = kp & 1;
          unsigned pA0 = cvtpk(stt[8 * u + 0], stt[8 * u + 1]);
          unsigned pA1 = cvtpk(stt[8 * u + 2], stt[8 * u + 3]);
          unsigned pB0 = cvtpk(stt[8 * u + 4], stt[8 * u + 5]);
          unsigned pB1 = cvtpk(stt[8 * u + 6], stt[8 * u + 7]);
          uint2v sw0 = plswap(pA0, pB0, hi);
          uint2v sw1 = plswap(pA1, pB1, hi);
          uint4v fv;
          fv[0] = sw0[0]; fv[1] = sw1[0]; fv[2] = sw0[1]; fv[3] = sw1[1];
          pf[kp] = __builtin_bit_cast(short8, fv);
        }

        __builtin_amdgcn_s_setprio(1);
#pragma unroll
        for (int kp = 0; kp < 4; ++kp) {
          const int sg = 2 * kp + hi;
          const ushort* vb = img + 8192 + half * 4096;
          short8 v0 = *(const short8*)(vb + c32 * 64 + ((sg ^ (c32 & 7)) << 3));
          short8 v1 = *(const short8*)(vb + (32 + c32) * 64 + ((sg ^ (c32 & 7)) << 3));
          acc0 = __builtin_amdgcn_mfma_f32_32x32x16_bf16(pf[kp], v0, acc0, 0, 0, 0);
          acc1 = __builtin_amdgcn_mfma_f32_32x32x16_bf16(pf[kp], v1, acc1, 0, 0, 0);
        }
        __builtin_amdgcn_s_setprio(0);
      }
    }

    if (more) swrite(SMn, nxt, tid);
    __syncthreads();
  }
}

// ---------------- main attention v19: split-S (additive fixed-max partials) --------
// grid (x=bh 32, y=24): y<16 -> split tile yi=y>>1 half=y&1 (yi<8, partials);
//                       y>=16 -> unsplit tile yi=y-8 (writes O directly).
__global__ __launch_bounds__(256, 2) void attn_fwd19(
    const float* __restrict__ Qg, const ushort* __restrict__ Kb,
    const ushort* __restrict__ Vt, float* __restrict__ pacc,
    float* __restrict__ pd, float* __restrict__ Og) {
  const int bh = (int)blockIdx.x;
  const int b = bh >> 4, h = bh & 15;
  const int y = (int)blockIdx.y;
  const int tid = (int)threadIdx.x;
  const int w = tid >> 6, lane = tid & 63;
  const int hi = lane >> 5, c32 = lane & 31;

  __shared__ __align__(16) ushort SM[2][16384];

  int yi, rs, re;
  bool split;
  if (y < 16) {
    split = true;
    yi = y >> 1;
    const int r0 = ((yi << 7) + 1) >> 7;  // = yi except yi=0 -> 0
    const int R = NR_ - r0;
    const int mid = r0 + ((R + 1) >> 1);
    rs = (y & 1) ? mid : r0;
    re = (y & 1) ? NR_ : mid;
  } else {
    split = false;
    yi = y - 8;                            // 8..15
    rs = ((yi << 7) + 1) >> 7;
    re = NR_;
  }
  const int q0 = yi << 7;

  f32x16 acc0, acc1;
  float dsum;
  int qbase, qrow;
  tile_body(Qg, Kb, Vt, SM[0], SM[1], b, h, bh, q0, rs, re, tid,
            acc0, acc1, dsum, qbase, qrow);

  if (split) {
    // write raw partials: pacc[((bh*8+yi)*2+half)][128 q][64 d], pd[...][128 q]
    const int half = y & 1;
    const size_t tb = (size_t)((bh * 8 + yi) * 2 + half);
    float* pa = pacc + tb * (128 * 64);
    float dfull = dsum + __shfl_xor(dsum, 32);
    if (hi == 0) pd[tb * 128 + (w << 5) + c32] = dfull;
#pragma unroll
    for (int r16 = 0; r16 < 16; ++r16) {
      const int row = (r16 & 3) + 8 * (r16 >> 2) + 4 * hi;
      const int ql = (w << 5) + row;
      pa[ql * 64 + c32] = acc0[r16];
      pa[ql * 64 + 32 + c32] = acc1[r16];
    }
  } else {
    // v17-verified epilogue (divide + direct O write)
    float dfull = dsum + __shfl_xor(dsum, 32);
#pragma unroll
    for (int r16 = 0; r16 < 16; ++r16) {
      const int row = (r16 & 3) + 8 * (r16 >> 2) + 4 * hi;
      const float dn = __shfl(dfull, row);
      const int grow = qbase + row;
      if (grow != L_ - 1) {
        const float inv = 1.0f / dn;
        const size_t base = ((size_t)((b * L_ + grow) * H_ + h)) * D_;
        Og[base + c32] = acc0[r16] * inv;
        Og[base + 32 + c32] = acc1[r16] * inv;
      }
    }
  }
}

// ---------------- merge split partials: O = (na+nb)/(da+db) ----------------
__global__ __launch_bounds__(256) void merge_split(const float* __restrict__ pacc,
                                                   const float* __restrict__ pd,
                                                   float* __restrict__ Og) {
  const int bh = (int)blockIdx.x, yi = (int)blockIdx.y;
  const int b = bh >> 4, h = bh & 15;
  const int tid = (int)threadIdx.x;
  const size_t t0 = (size_t)((bh * 8 + yi) * 2);
  const float* pa = pacc + t0 * (128 * 64);
  const float* pb = pa + 128 * 64;
  const int q0 = yi << 7;
#pragma unroll
  for (int i = 0; i < 32; ++i) {
    const int e = tid + (i << 8);        // 0..8191
    const int ql = e >> 6, d = e & 63;
    const float dn = pd[t0 * 128 + ql] + pd[(t0 + 1) * 128 + ql];
    const float num = pa[e] + pb[e];
    Og[((size_t)((b * L_ + q0 + ql) * H_ + h)) * D_ + d] = num / dn;
  }
}

// ---------------- main attention v17 (verified R17; ws-small path) ----------------
__global__ __launch_bounds__(256, 2) void attn_fwd17(
    const float* __restrict__ Qg, const ushort* __restrict__ Kb,
    const ushort* __restrict__ Vt, float* __restrict__ Og) {
  const int bh = (int)blockIdx.x;
  const int b = bh >> 4, h = bh & 15;
  const int yi0 = (int)blockIdx.y;
  const int yi = (yi0 < 8) ? yi0 : 23 - yi0;
  const int q0 = yi << 7;
  const int tid = (int)threadIdx.x;
  const int w = tid >> 6, lane = tid & 63;
  const int hi = lane >> 5, c32 = lane & 31;

  __shared__ __align__(16) ushort SM[2][16384];

  const int rs = (q0 + 1) >> 7;
  f32x16 acc0, acc1;
  float dsum;
  int qbase, qrow;
  tile_body(Qg, Kb, Vt, SM[0], SM[1], b, h, bh, q0, rs, NR_, tid,
            acc0, acc1, dsum, qbase, qrow);

  float dfull = dsum + __shfl_xor(dsum, 32);
#pragma unroll
  for (int r16 = 0; r16 < 16; ++r16) {
    const int row = (r16 & 3) + 8 * (r16 >> 2) + 4 * hi;
    const float dn = __shfl(dfull, row);
    const int grow = qbase + row;
    if (grow != L_ - 1) {
      const float inv = 1.0f / dn;
      const size_t base = ((size_t)((b * L_ + grow) * H_ + h)) * D_;
      Og[base + c32] = acc0[r16] * inv;
      Og[base + 32 + c32] = acc1[r16] * inv;
    }
  }
}

// ---------------- row L-1 = mean(V): combine 32 prep partials (R15-verified) --------
__global__ __launch_bounds__(64) void vmean_comb(const float* __restrict__ part,
                                                 float* __restrict__ Og) {
  const int bh = blockIdx.x;
  const int b = bh >> 4, h = bh & 15;
  const int lane = (int)threadIdx.x;
  float t = 0.f;
#pragma unroll
  for (int i = 0; i < 32; ++i) t += part[(size_t)(bh * 32 + i) * 64 + lane];
  Og[((size_t)((b * L_ + (L_ - 1)) * H_ + h)) * D_ + lane] = t * (1.0f / (float)S_);
}

// ---------------- fallback path (v2, fp32-direct, no ws; verified) ----------------
__global__ __launch_bounds__(256) void attn_fwd(
    const float* __restrict__ Qg, const float* __restrict__ Kg,
    const float* __restrict__ Vg, float* __restrict__ Og) {
  const int bh = blockIdx.x;
  const int b = bh >> 4, h = bh & 15;
  const int q0 = blockIdx.y << 6;
  const int tid = (int)threadIdx.x;
  const int lane = tid & 63;
  const int w = tid >> 6;
  const int gp = lane >> 4;
  const int c = lane & 15;
  const int qbase = q0 + (w << 4);

  __shared__ unsigned short Kl[32][72];
  __shared__ unsigned short Vts[64][40];

  short8 qf0, qf1;
  {
    const float* qrow = Qg + ((size_t)((b * L_ + (qbase + c)) * H_ + h)) * E_;
    const f32x4* q0p = (const f32x4*)(qrow + (gp << 3));
    const f32x4* q1p = (const f32x4*)(qrow + 32 + (gp << 3));
    f32x4 a0 = q0p[0], b0 = q0p[1], a1 = q1p[0], b1 = q1p[1];
    float t0[8] = {a0[0],a0[1],a0[2],a0[3],b0[0],b0[1],b0[2],b0[3]};
    float t1[8] = {a1[0],a1[1],a1[2],a1[3],b1[0],b1[1],b1[2],b1[3]};
#pragma unroll
    for (int j = 0; j < 8; ++j) {
      qf0[j] = (short)f2bf(0.125f * t0[j]);
      qf1[j] = (short)f2bf(0.125f * t1[j]);
    }
  }

  f32x4 accO[4];
#pragma unroll
  for (int k0 = 0; k0 < 4; ++k0) accO[k0] = (f32x4){0.f, 0.f, 0.f, 0.f};
  float m_run = -1e30f, denom = 0.f;

  const int c0 = (q0 + 1) >> 5;
  const int srow = tid >> 3;
  const int scol = (tid & 7) << 3;

  for (int ch = c0; ch < (S_ >> 5); ++ch) {
    const int s0 = ch << 5;
    __syncthreads();
    {
      const size_t rbase = ((size_t)((b * S_ + (s0 + srow)) * H_ + h));
      const float* kp = Kg + rbase * E_ + scol;
      f32x4 ka = *(const f32x4*)kp;
      f32x4 kb = *(const f32x4*)(kp + 4);
      short8 kv;
      kv[0]=(short)f2bf(ka[0]); kv[1]=(short)f2bf(ka[1]);
      kv[2]=(short)f2bf(ka[2]); kv[3]=(short)f2bf(ka[3]);
      kv[4]=(short)f2bf(kb[0]); kv[5]=(short)f2bf(kb[1]);
      kv[6]=(short)f2bf(kb[2]); kv[7]=(short)f2bf(kb[3]);
      *(short8*)&Kl[srow][scol] = kv;
      const float* vp = Vg + rbase * D_ + scol;
      f32x4 va = *(const f32x4*)vp;
      f32x4 vb = *(const f32x4*)(vp + 4);
      Vts[scol + 0][srow] = f2bf(va[0]);
      Vts[scol + 1][srow] = f2bf(va[1]);
      Vts[scol + 2][srow] = f2bf(va[2]);
      Vts[scol + 3][srow] = f2bf(va[3]);
      Vts[scol + 4][srow] = f2bf(vb[0]);
      Vts[scol + 5][srow] = f2bf(vb[1]);
      Vts[scol + 6][srow] = f2bf(vb[2]);
      Vts[scol + 7][srow] = f2bf(vb[3]);
    }
    __syncthreads();
    if (s0 + 31 <= qbase) continue;

    f32x4 st0 = {0.f,0.f,0.f,0.f}, st1 = {0.f,0.f,0.f,0.f};
    {
      short8 kf;
      kf = *(const short8*)&Kl[c][(gp << 3)];
      st0 = __builtin_amdgcn_mfma_f32_16x16x32_bf16(kf, qf0, st0, 0, 0, 0);
      kf = *(const short8*)&Kl[c][32 + (gp << 3)];
      st0 = __builtin_amdgcn_mfma_f32_16x16x32_bf16(kf, qf1, st0, 0, 0, 0);
      kf = *(const short8*)&Kl[16 + c][(gp << 3)];
      st1 = __builtin_amdgcn_mfma_f32_16x16x32_bf16(kf, qf0, st1, 0, 0, 0);
      kf = *(const short8*)&Kl[16 + c][32 + (gp << 3)];
      st1 = __builtin_amdgcn_mfma_f32_16x16x32_bf16(kf, qf1, st1, 0, 0, 0);
    }

    const int lrow = qbase + c;
    float p[8];
    {
      float sarr[8] = {st0[0], st0[1], st0[2], st0[3], st1[0], st1[1], st1[2], st1[3]};
      float mx = -1e30f;
#pragma unroll
      for (int i = 0; i < 8; ++i) {
        int sg = s0 + ((i >> 2) << 4) + (gp << 2) + (i & 3);
        float v = (sg > lrow) ? sarr[i] : -1e30f;
        p[i] = v;
        mx = fmaxf(mx, v);
      }
      mx = fmaxf(mx, __shfl_xor(mx, 16));
      mx = fmaxf(mx, __shfl_xor(mx, 32));
      float m_new = fmaxf(m_run, mx);
      float sum = 0.f;
#pragma unroll
      for (int i = 0; i < 8; ++i) { p[i] = __expf(p[i] - m_new); sum += p[i]; }
      sum += __shfl_xor(sum, 16);
      sum += __shfl_xor(sum, 32);
      float alpha = __expf(m_run - m_new);
      m_run = m_new;
      denom = denom * alpha + sum;
      float ar0 = __shfl(alpha, (gp << 2) + 0);
      float ar1 = __shfl(alpha, (gp << 2) + 1);
      float ar2 = __shfl(alpha, (gp << 2) + 2);
      float ar3 = __shfl(alpha, (gp << 2) + 3);
#pragma unroll
      for (int k0 = 0; k0 < 4; ++k0) {
        accO[k0][0] *= ar0; accO[k0][1] *= ar1;
        accO[k0][2] *= ar2; accO[k0][3] *= ar3;
      }
    }

    {
      unsigned int pA0 = pkbf(p[0], p[1]), pA1 = pkbf(p[2], p[3]);
      unsigned int pB0 = pkbf(p[4], p[5]), pB1 = pkbf(p[6], p[7]);
      const int al = (gp << 1) & 3;
      const int src0 = (al << 4) + c, src1 = src0 + 16;
      unsigned int a0 = (unsigned int)__shfl((int)pA0, src0);
      unsigned int a1 = (unsigned int)__shfl((int)pA1, src0);
      unsigned int a2 = (unsigned int)__shfl((int)pA0, src1);
      unsigned int a3 = (unsigned int)__shfl((int)pA1, src1);
      unsigned int b0 = (unsigned int)__shfl((int)pB0, src0);
      unsigned int b1 = (unsigned int)__shfl((int)pB1, src0);
      unsigned int b2 = (unsigned int)__shfl((int)pB0, src1);
      unsigned int b3 = (unsigned int)__shfl((int)pB1, src1);
      const bool useA = (gp < 2);
      uint4v fv;
      fv[0] = useA ? a0 : b0;
      fv[1] = useA ? a1 : b1;
      fv[2] = useA ? a2 : b2;
      fv[3] = useA ? a3 : b3;
      short8 pfv = __builtin_bit_cast(short8, fv);
#pragma unroll
      for (int k0 = 0; k0 < 4; ++k0) {
        short8 vf = *(const short8*)&Vts[(k0 << 4) + c][(gp << 3)];
        accO[k0] = __builtin_amdgcn_mfma_f32_16x16x32_bf16(pfv, vf, accO[k0], 0, 0, 0);
      }
    }
  }

  float dr[4];
  dr[0] = __shfl(denom, (gp << 2) + 0);
  dr[1] = __shfl(denom, (gp << 2) + 1);
  dr[2] = __shfl(denom, (gp << 2) + 2);
  dr[3] = __shfl(denom, (gp << 2) + 3);
#pragma unroll
  for (int r = 0; r < 4; ++r) {
    const int grow = qbase + (gp << 2) + r;
    if (grow == L_ - 1) continue;
    const size_t base = ((size_t)((b * L_ + grow) * H_ + h)) * D_ + c;
    const float inv = 1.0f / dr[r];
    Og[base +  0] = accO[0][r] * inv;
    Og[base + 16] = accO[1][r] * inv;
    Og[base + 32] = accO[2][r] * inv;
    Og[base + 48] = accO[3][r] * inv;
  }
}

__global__ __launch_bounds__(256) void vmean_fix(const float* __restrict__ Vg,
                                                 float* __restrict__ Og) {
  const int bh = blockIdx.x;
  const int b = bh >> 4, h = bh & 15;
  const int t = (int)threadIdx.x;
  const int lane = t & 63, w = t >> 6;
  float sum = 0.f;
  for (int s = w; s < S_; s += 4)
    sum += Vg[((size_t)((b * S_ + s) * H_ + h)) * D_ + lane];
  __shared__ float red[4][64];
  red[w][lane] = sum;
  __syncthreads();
  if (w == 0) {
    float tot = red[0][lane] + red[1][lane] + red[2][lane] + red[3][lane];
    Og[((size_t)((b * L_ + (L_ - 1)) * H_ + h)) * D_ + lane] = tot * (1.0f / (float)S_);
  }
}

extern "C" void kernel_launch(void* const* d_in, const int* in_sizes, int n_in,
                              void* d_out, int out_size, void* d_ws, size_t ws_size,
                              hipStream_t stream) {
  const float* Q = (const float*)d_in[0];
  const float* K = (const float*)d_in[1];
  const float* V = (const float*)d_in[2];
  float* O = (float*)d_out;
  const size_t szK = (size_t)B_ * H_ * S_ * E_ * 2;    // 8 MB bf16 K
  const size_t szV = (size_t)B_ * H_ * D_ * S_ * 2;    // 8 MB bf16 V^T
  const size_t szP = (size_t)(B_ * H_ * 32) * 64 * 4;  // 256 KB partials
  const size_t szA = (size_t)32 * 8 * 2 * 128 * 64 * 4; // 16.8 MB split numerators
  const size_t szD = (size_t)32 * 8 * 2 * 128 * 4;      // 256 KB split denoms

  if (ws_size >= szK + szV + szP + szA + szD) {
    ushort* Kb = (ushort*)d_ws;
    ushort* Vt = (ushort*)((char*)d_ws + szK);
    float* part = (float*)((char*)d_ws + szK + szV);
    float* pacc = (float*)((char*)d_ws + szK + szV + szP);
    float* pd = (float*)((char*)d_ws + szK + szV + szP + szA);
    prep_all<<<dim3(3072), dim3(256), 0, stream>>>(K, V, Kb, Vt, part);
    attn_fwd19<<<dim3(32, 24), dim3(256), 0, stream>>>(Q, Kb, Vt, pacc, pd, O);
    merge_split<<<dim3(32, 8), dim3(256), 0, stream>>>(pacc, pd, O);
    vmean_comb<<<dim3(B_ * H_), dim3(64), 0, stream>>>(part, O);
  } else if (ws_size >= szK + szV + szP) {
    ushort* Kb = (ushort*)d_ws;
    ushort* Vt = (ushort*)((char*)d_ws + szK);
    float* part = (float*)((char*)d_ws + szK + szV);
    prep_all<<<dim3(3072), dim3(256), 0, stream>>>(K, V, Kb, Vt, part);
    attn_fwd17<<<dim3(B_ * H_, L_ / 128), dim3(256), 0, stream>>>(Q, Kb, Vt, O);
    vmean_comb<<<dim3(B_ * H_), dim3(64), 0, stream>>>(part, O);
  } else {
    attn_fwd<<<dim3(B_ * H_, L_ / 64), dim3(256), 0, stream>>>(Q, K, V, O);
    vmean_fix<<<dim3(B_ * H_), dim3(256), 0, stream>>>(V, O);
  }
}

// Round 20
// 61.188 us; speedup vs baseline: 1.1988x; 1.1988x over previous
//
#include <hip/hip_runtime.h>

// Anti-causal attention (key s valid iff s > l), scale=1/8 after masking.
// Row L-1 fully masked -> softmax uniform -> out = mean(V).
// B=2, L=S=2048, H=16, E=D=64, fp32 in/out, bf16 MFMA compute.
// v20 == v17 (best verified, R17: 61.2us total). Session-final restore.
//   - prep_all: K->bf16 [bh][s][e], V->bf16^T [bh][d][s], V partial means
//   - attn: 128q/4-wave blocks, 128-key dbuf rounds, swapped-QK 32x32x16 MFMA,
//     fixed-max softmax (exp2(st-16), exact: 2^-16 cancels in division),
//     T12 cvt_pk+permlane32_swap P-packing, bh-major grid (XCD L2 affinity)
//   - vmean_comb: row L-1 = mean(V) from prep partials

#define B_ 2
#define L_ 2048
#define H_ 16
#define E_ 64
#define S_ 2048
#define D_ 64
#define NR_ 16              /* S/128 rounds */
#define CSH 16.0f           /* fixed exp2 shift (integer => exact) */
#define QSCALE 0.18033688011112042f /* 0.125 * log2(e) */

typedef __attribute__((ext_vector_type(4))) float f32x4;
typedef __attribute__((ext_vector_type(16))) float f32x16;
typedef __attribute__((ext_vector_type(8))) short short8;
typedef __attribute__((ext_vector_type(2))) unsigned int uint2v;
typedef __attribute__((ext_vector_type(4))) unsigned int uint4v;
typedef unsigned short ushort;

__device__ __forceinline__ unsigned short f2bf(float f) {
  unsigned int u = __builtin_bit_cast(unsigned int, f);
  u = (u + 0x7FFFu + ((u >> 16) & 1u)) >> 16;  // RNE
  return (unsigned short)u;
}
__device__ __forceinline__ unsigned int pkbf(float a, float b) {
  return (unsigned int)f2bf(a) | ((unsigned int)f2bf(b) << 16);
}
__device__ __forceinline__ unsigned cvtpk(float a, float b) {
  unsigned r;
  asm("v_cvt_pk_bf16_f32 %0, %1, %2" : "=v"(r) : "v"(a), "v"(b));
  return r;
}
__device__ __forceinline__ uint2v plswap(unsigned a, unsigned b, int hi) {
#if __has_builtin(__builtin_amdgcn_permlane32_swap)
  (void)hi;
  return __builtin_amdgcn_permlane32_swap(a, b, false, false);
#else
  unsigned ax = (unsigned)__shfl_xor((int)a, 32);
  unsigned bx = (unsigned)__shfl_xor((int)b, 32);
  uint2v r;
  r[0] = hi ? bx : a;
  r[1] = hi ? b : ax;
  return r;
#endif
}
__device__ __forceinline__ f32x16 zero16() {
  f32x16 z;
#pragma unroll
  for (int i = 0; i < 16; ++i) z[i] = 0.f;
  return z;
}

// -------- fused prep (R15-verified) + V partial-means --------
__global__ __launch_bounds__(256) void prep_all(const float* __restrict__ Kg,
                                                const float* __restrict__ Vg,
                                                ushort* __restrict__ Kb,
                                                ushort* __restrict__ Vt,
                                                float* __restrict__ part) {
  __shared__ ushort Tl[64][72];
  const int blk = (int)blockIdx.x;
  const int tid = (int)threadIdx.x;
  if (blk < 2048) {  // K path (R10-verified)
    const int t = blk * 256 + tid;
    const int orow = t >> 3, e0 = (t & 7) << 3;
    const int s = orow & (S_ - 1), bh = orow >> 11;
    const int b = bh >> 4, h = bh & 15;
    const float* src = Kg + ((size_t)((b * S_ + s) * H_ + h)) * E_ + e0;
    f32x4 a = ((const f32x4*)src)[0], c = ((const f32x4*)src)[1];
    short8 o;
    o[0]=(short)f2bf(a[0]); o[1]=(short)f2bf(a[1]); o[2]=(short)f2bf(a[2]); o[3]=(short)f2bf(a[3]);
    o[4]=(short)f2bf(c[0]); o[5]=(short)f2bf(c[1]); o[6]=(short)f2bf(c[2]); o[7]=(short)f2bf(c[3]);
    *(short8*)(Kb + (size_t)orow * E_ + e0) = o;
  } else {  // V path (R10-verified) + partial means (R15-verified)
    const int vb = blk - 2048;
    const int bh = vb & 31, st = vb >> 5;
    const int b = bh >> 4, h = bh & 15;
    const int s0 = st << 6;
    {
      const int sr = tid >> 2, d0 = (tid & 3) << 4;
      const float* src = Vg + ((size_t)((b * S_ + s0 + sr) * H_ + h)) * D_ + d0;
      f32x4 v0 = ((const f32x4*)src)[0], v1 = ((const f32x4*)src)[1];
      f32x4 v2 = ((const f32x4*)src)[2], v3 = ((const f32x4*)src)[3];
      ushort* dst = &Tl[sr][d0];
      dst[0]=f2bf(v0[0]); dst[1]=f2bf(v0[1]); dst[2]=f2bf(v0[2]); dst[3]=f2bf(v0[3]);
      dst[4]=f2bf(v1[0]); dst[5]=f2bf(v1[1]); dst[6]=f2bf(v1[2]); dst[7]=f2bf(v1[3]);
      dst[8]=f2bf(v2[0]); dst[9]=f2bf(v2[1]); dst[10]=f2bf(v2[2]); dst[11]=f2bf(v2[3]);
      dst[12]=f2bf(v3[0]); dst[13]=f2bf(v3[1]); dst[14]=f2bf(v3[2]); dst[15]=f2bf(v3[3]);
    }
    __syncthreads();
    {
      const int d = tid >> 2, sb = (tid & 3) << 4;
      short8 o0, o1;
#pragma unroll
      for (int j = 0; j < 8; ++j) {
        o0[j] = (short)Tl[sb + j][d];
        o1[j] = (short)Tl[sb + 8 + j][d];
      }
      ushort* dst = Vt + ((size_t)bh * D_ + d) * S_ + s0 + sb;
      *(short8*)dst = o0;
      *(short8*)(dst + 8) = o1;
    }
    if (tid < 64) {
      float sum = 0.f;
#pragma unroll 8
      for (int s = 0; s < 64; ++s)
        sum += __builtin_bit_cast(float, (unsigned)Tl[s][tid] << 16);
      part[(size_t)(bh * 32 + st) * 64 + tid] = sum;
    }
  }
}

// ---------------- staging (v9-verified, verbatim): 128-key image ----------------
struct Stage8 { short8 k[4]; short8 v[4]; };

__device__ __forceinline__ Stage8 sload(const ushort* __restrict__ Kbh,
                                        const ushort* __restrict__ VbhT,
                                        int s0, int tid) {
  Stage8 r;
  const int sl = tid >> 1, gb = (tid & 1) * 4;
  const ushort* kp = Kbh + (size_t)(s0 + sl) * E_ + gb * 8;
  r.k[0] = *(const short8*)(kp);
  r.k[1] = *(const short8*)(kp + 8);
  r.k[2] = *(const short8*)(kp + 16);
  r.k[3] = *(const short8*)(kp + 24);
  const int d = tid >> 2, sb = (tid & 3) * 32;
  const ushort* vp = VbhT + (size_t)d * S_ + s0 + sb;
  r.v[0] = *(const short8*)(vp);
  r.v[1] = *(const short8*)(vp + 8);
  r.v[2] = *(const short8*)(vp + 16);
  r.v[3] = *(const short8*)(vp + 24);
  return r;
}

__device__ __forceinline__ void swrite(ushort* SM, const Stage8& r, int tid) {
  const int sl = tid >> 1, gb = (tid & 1) * 4;
#pragma unroll
  for (int j = 0; j < 4; ++j)
    *(short8*)(SM + sl * 64 + (((gb + j) ^ (sl & 7)) << 3)) = r.k[j];
  const int d = tid >> 2, sgb = (tid & 3) * 4;
#pragma unroll
  for (int j = 0; j < 4; ++j) {
    const int sgg = sgb + j;
    *(short8*)(SM + 8192 + (sgg >> 3) * 4096 + d * 64 + (((sgg & 7) ^ (d & 7)) << 3)) = r.v[j];
  }
}

// ---------------- main attention (v17, verified R17) ----------------
__global__ __launch_bounds__(256, 2) void attn_fwd17(
    const float* __restrict__ Qg, const ushort* __restrict__ Kb,
    const ushort* __restrict__ Vt, float* __restrict__ Og) {
  const int bh = (int)blockIdx.x;
  const int b = bh >> 4, h = bh & 15;
  const int yi0 = (int)blockIdx.y;
  const int yi = (yi0 < 8) ? yi0 : 23 - yi0;  // balanced heavy+light remap
  const int q0 = yi << 7;                     // 128 q-rows per block
  const int tid = (int)threadIdx.x;
  const int w = tid >> 6, lane = tid & 63;
  const int hi = lane >> 5, c32 = lane & 31;
  const int qbase = q0 + (w << 5);
  const int qrow = qbase + c32;

  __shared__ __align__(16) ushort SM[2][16384];  // dbuf: 2 x (K 16KB | V 16KB)

  const ushort* Kbh = Kb + (size_t)bh * (S_ * E_);
  const ushort* VbhT = Vt + (size_t)bh * (D_ * S_);

  short8 qf[4];
  {
    const float* qr = Qg + ((size_t)((b * L_ + qrow) * H_ + h)) * E_;
#pragma unroll
    for (int kc = 0; kc < 4; ++kc) {
      f32x4 x = *(const f32x4*)(qr + kc * 16 + hi * 8);
      f32x4 y = *(const f32x4*)(qr + kc * 16 + hi * 8 + 4);
      short8 q;
      q[0]=(short)f2bf(QSCALE*x[0]); q[1]=(short)f2bf(QSCALE*x[1]);
      q[2]=(short)f2bf(QSCALE*x[2]); q[3]=(short)f2bf(QSCALE*x[3]);
      q[4]=(short)f2bf(QSCALE*y[0]); q[5]=(short)f2bf(QSCALE*y[1]);
      q[6]=(short)f2bf(QSCALE*y[2]); q[7]=(short)f2bf(QSCALE*y[3]);
      qf[kc] = q;
    }
  }

  f32x16 acc0 = zero16(), acc1 = zero16();
  float dsum = 0.f;

  const int r0 = (q0 + 1) >> 7;

  {
    Stage8 s = sload(Kbh, VbhT, r0 << 7, tid);
    swrite(SM[0], s, tid);
  }
  __syncthreads();

  for (int r = r0; r < NR_; ++r) {
    const int cur = (r - r0) & 1;
    const bool more = (r + 1) < NR_;
    Stage8 nxt;
    if (more) nxt = sload(Kbh, VbhT, (r + 1) << 7, tid);  // issue early (T14)

    const ushort* img = SM[cur];
#pragma unroll
    for (int half = 0; half < 2; ++half) {
      const int s0 = (r << 7) + (half << 6);
      if (s0 + 63 > qbase) {
        // ---- QK^T (swapped)
        f32x16 st0 = zero16(), st1 = zero16();
        __builtin_amdgcn_s_setprio(1);
#pragma unroll
        for (int kc = 0; kc < 4; ++kc) {
          const int gg = 2 * kc + hi;
          const int rl0 = (half << 6) + c32, rl1 = rl0 + 32;
          short8 k0 = *(const short8*)(img + rl0 * 64 + ((gg ^ (rl0 & 7)) << 3));
          short8 k1 = *(const short8*)(img + rl1 * 64 + ((gg ^ (rl1 & 7)) << 3));
          st0 = __builtin_amdgcn_mfma_f32_32x32x16_bf16(k0, qf[kc], st0, 0, 0, 0);
          st1 = __builtin_amdgcn_mfma_f32_32x32x16_bf16(k1, qf[kc], st1, 0, 0, 0);
        }
        __builtin_amdgcn_s_setprio(0);

        // ---- mask (straddling chunks only)
        if (s0 < qbase + 32) {
#pragma unroll
          for (int r16 = 0; r16 < 16; ++r16) {
            const int ko = (r16 & 3) + 8 * (r16 >> 2) + 4 * hi;
            st0[r16] = (s0 + ko <= qrow) ? -1e30f : st0[r16];
            st1[r16] = (s0 + 32 + ko <= qrow) ? -1e30f : st1[r16];
          }
        }

        // ---- fixed-max softmax: p = exp2(st - 16), exact (R17-verified)
        float ps = 0.f;
#pragma unroll
        for (int r16 = 0; r16 < 16; ++r16) { st0[r16] = exp2f(st0[r16] - CSH); ps += st0[r16]; }
#pragma unroll
        for (int r16 = 0; r16 < 16; ++r16) { st1[r16] = exp2f(st1[r16] - CSH); ps += st1[r16]; }
        dsum += ps;

        // ---- P -> A fragments: cvt_pk + permlane32_swap (T12)
        short8 pf[4];
#pragma unroll
        for (int kp = 0; kp < 4; ++kp) {
          const f32x16 stt = (kp < 2) ? st0 : st1;
          const int u = kp & 1;
          unsigned pA0 = cvtpk(stt[8 * u + 0], stt[8 * u + 1]);
          unsigned pA1 = cvtpk(stt[8 * u + 2], stt[8 * u + 3]);
          unsigned pB0 = cvtpk(stt[8 * u + 4], stt[8 * u + 5]);
          unsigned pB1 = cvtpk(stt[8 * u + 6], stt[8 * u + 7]);
          uint2v sw0 = plswap(pA0, pB0, hi);
          uint2v sw1 = plswap(pA1, pB1, hi);
          uint4v fv;
          fv[0] = sw0[0]; fv[1] = sw1[0]; fv[2] = sw0[1]; fv[3] = sw1[1];
          pf[kp] = __builtin_bit_cast(short8, fv);
        }

        // ---- PV
        __builtin_amdgcn_s_setprio(1);
#pragma unroll
        for (int kp = 0; kp < 4; ++kp) {
          const int sg = 2 * kp + hi;
          const ushort* vb = img + 8192 + half * 4096;
          short8 v0 = *(const short8*)(vb + c32 * 64 + ((sg ^ (c32 & 7)) << 3));
          short8 v1 = *(const short8*)(vb + (32 + c32) * 64 + ((sg ^ (c32 & 7)) << 3));
          acc0 = __builtin_amdgcn_mfma_f32_32x32x16_bf16(pf[kp], v0, acc0, 0, 0, 0);
          acc1 = __builtin_amdgcn_mfma_f32_32x32x16_bf16(pf[kp], v1, acc1, 0, 0, 0);
        }
        __builtin_amdgcn_s_setprio(0);
      }
    }

    if (more) swrite(SM[cur ^ 1], nxt, tid);  // other buffer: no read conflict
    __syncthreads();                           // one barrier per 128 keys
  }

  // ---- epilogue (dsum in 2^-16-scaled units; cancels in the division)
  float dfull = dsum + __shfl_xor(dsum, 32);
#pragma unroll
  for (int r16 = 0; r16 < 16; ++r16) {
    const int row = (r16 & 3) + 8 * (r16 >> 2) + 4 * hi;
    const float dn = __shfl(dfull, row);
    const int grow = qbase + row;
    if (grow != L_ - 1) {
      const float inv = 1.0f / dn;
      const size_t base = ((size_t)((b * L_ + grow) * H_ + h)) * D_;
      Og[base + c32] = acc0[r16] * inv;
      Og[base + 32 + c32] = acc1[r16] * inv;
    }
  }
}

// ---------------- row L-1 = mean(V): combine 32 prep partials (R15-verified) --------
__global__ __launch_bounds__(64) void vmean_comb(const float* __restrict__ part,
                                                 float* __restrict__ Og) {
  const int bh = blockIdx.x;
  const int b = bh >> 4, h = bh & 15;
  const int lane = (int)threadIdx.x;
  float t = 0.f;
#pragma unroll
  for (int i = 0; i < 32; ++i) t += part[(size_t)(bh * 32 + i) * 64 + lane];
  Og[((size_t)((b * L_ + (L_ - 1)) * H_ + h)) * D_ + lane] = t * (1.0f / (float)S_);
}

// ---------------- fallback path (v2, fp32-direct, no ws; verified) ----------------
__global__ __launch_bounds__(256) void attn_fwd(
    const float* __restrict__ Qg, const float* __restrict__ Kg,
    const float* __restrict__ Vg, float* __restrict__ Og) {
  const int bh = blockIdx.x;
  const int b = bh >> 4, h = bh & 15;
  const int q0 = blockIdx.y << 6;
  const int tid = (int)threadIdx.x;
  const int lane = tid & 63;
  const int w = tid >> 6;
  const int gp = lane >> 4;
  const int c = lane & 15;
  const int qbase = q0 + (w << 4);

  __shared__ unsigned short Kl[32][72];
  __shared__ unsigned short Vts[64][40];

  short8 qf0, qf1;
  {
    const float* qrow = Qg + ((size_t)((b * L_ + (qbase + c)) * H_ + h)) * E_;
    const f32x4* q0p = (const f32x4*)(qrow + (gp << 3));
    const f32x4* q1p = (const f32x4*)(qrow + 32 + (gp << 3));
    f32x4 a0 = q0p[0], b0 = q0p[1], a1 = q1p[0], b1 = q1p[1];
    float t0[8] = {a0[0],a0[1],a0[2],a0[3],b0[0],b0[1],b0[2],b0[3]};
    float t1[8] = {a1[0],a1[1],a1[2],a1[3],b1[0],b1[1],b1[2],b1[3]};
#pragma unroll
    for (int j = 0; j < 8; ++j) {
      qf0[j] = (short)f2bf(0.125f * t0[j]);
      qf1[j] = (short)f2bf(0.125f * t1[j]);
    }
  }

  f32x4 accO[4];
#pragma unroll
  for (int k0 = 0; k0 < 4; ++k0) accO[k0] = (f32x4){0.f, 0.f, 0.f, 0.f};
  float m_run = -1e30f, denom = 0.f;

  const int c0 = (q0 + 1) >> 5;
  const int srow = tid >> 3;
  const int scol = (tid & 7) << 3;

  for (int ch = c0; ch < (S_ >> 5); ++ch) {
    const int s0 = ch << 5;
    __syncthreads();
    {
      const size_t rbase = ((size_t)((b * S_ + (s0 + srow)) * H_ + h));
      const float* kp = Kg + rbase * E_ + scol;
      f32x4 ka = *(const f32x4*)kp;
      f32x4 kb = *(const f32x4*)(kp + 4);
      short8 kv;
      kv[0]=(short)f2bf(ka[0]); kv[1]=(short)f2bf(ka[1]);
      kv[2]=(short)f2bf(ka[2]); kv[3]=(short)f2bf(ka[3]);
      kv[4]=(short)f2bf(kb[0]); kv[5]=(short)f2bf(kb[1]);
      kv[6]=(short)f2bf(kb[2]); kv[7]=(short)f2bf(kb[3]);
      *(short8*)&Kl[srow][scol] = kv;
      const float* vp = Vg + rbase * D_ + scol;
      f32x4 va = *(const f32x4*)vp;
      f32x4 vb = *(const f32x4*)(vp + 4);
      Vts[scol + 0][srow] = f2bf(va[0]);
      Vts[scol + 1][srow] = f2bf(va[1]);
      Vts[scol + 2][srow] = f2bf(va[2]);
      Vts[scol + 3][srow] = f2bf(va[3]);
      Vts[scol + 4][srow] = f2bf(vb[0]);
      Vts[scol + 5][srow] = f2bf(vb[1]);
      Vts[scol + 6][srow] = f2bf(vb[2]);
      Vts[scol + 7][srow] = f2bf(vb[3]);
    }
    __syncthreads();
    if (s0 + 31 <= qbase) continue;

    f32x4 st0 = {0.f,0.f,0.f,0.f}, st1 = {0.f,0.f,0.f,0.f};
    {
      short8 kf;
      kf = *(const short8*)&Kl[c][(gp << 3)];
      st0 = __builtin_amdgcn_mfma_f32_16x16x32_bf16(kf, qf0, st0, 0, 0, 0);
      kf = *(const short8*)&Kl[c][32 + (gp << 3)];
      st0 = __builtin_amdgcn_mfma_f32_16x16x32_bf16(kf, qf1, st0, 0, 0, 0);
      kf = *(const short8*)&Kl[16 + c][(gp << 3)];
      st1 = __builtin_amdgcn_mfma_f32_16x16x32_bf16(kf, qf0, st1, 0, 0, 0);
      kf = *(const short8*)&Kl[16 + c][32 + (gp << 3)];
      st1 = __builtin_amdgcn_mfma_f32_16x16x32_bf16(kf, qf1, st1, 0, 0, 0);
    }

    const int lrow = qbase + c;
    float p[8];
    {
      float sarr[8] = {st0[0], st0[1], st0[2], st0[3], st1[0], st1[1], st1[2], st1[3]};
      float mx = -1e30f;
#pragma unroll
      for (int i = 0; i < 8; ++i) {
        int sg = s0 + ((i >> 2) << 4) + (gp << 2) + (i & 3);
        float v = (sg > lrow) ? sarr[i] : -1e30f;
        p[i] = v;
        mx = fmaxf(mx, v);
      }
      mx = fmaxf(mx, __shfl_xor(mx, 16));
      mx = fmaxf(mx, __shfl_xor(mx, 32));
      float m_new = fmaxf(m_run, mx);
      float sum = 0.f;
#pragma unroll
      for (int i = 0; i < 8; ++i) { p[i] = __expf(p[i] - m_new); sum += p[i]; }
      sum += __shfl_xor(sum, 16);
      sum += __shfl_xor(sum, 32);
      float alpha = __expf(m_run - m_new);
      m_run = m_new;
      denom = denom * alpha + sum;
      float ar0 = __shfl(alpha, (gp << 2) + 0);
      float ar1 = __shfl(alpha, (gp << 2) + 1);
      float ar2 = __shfl(alpha, (gp << 2) + 2);
      float ar3 = __shfl(alpha, (gp << 2) + 3);
#pragma unroll
      for (int k0 = 0; k0 < 4; ++k0) {
        accO[k0][0] *= ar0; accO[k0][1] *= ar1;
        accO[k0][2] *= ar2; accO[k0][3] *= ar3;
      }
    }

    {
      unsigned int pA0 = pkbf(p[0], p[1]), pA1 = pkbf(p[2], p[3]);
      unsigned int pB0 = pkbf(p[4], p[5]), pB1 = pkbf(p[6], p[7]);
      const int al = (gp << 1) & 3;
      const int src0 = (al << 4) + c, src1 = src0 + 16;
      unsigned int a0 = (unsigned int)__shfl((int)pA0, src0);
      unsigned int a1 = (unsigned int)__shfl((int)pA1, src0);
      unsigned int a2 = (unsigned int)__shfl((int)pA0, src1);
      unsigned int a3 = (unsigned int)__shfl((int)pA1, src1);
      unsigned int b0 = (unsigned int)__shfl((int)pB0, src0);
      unsigned int b1 = (unsigned int)__shfl((int)pB1, src0);
      unsigned int b2 = (unsigned int)__shfl((int)pB0, src1);
      unsigned int b3 = (unsigned int)__shfl((int)pB1, src1);
      const bool useA = (gp < 2);
      uint4v fv;
      fv[0] = useA ? a0 : b0;
      fv[1] = useA ? a1 : b1;
      fv[2] = useA ? a2 : b2;
      fv[3] = useA ? a3 : b3;
      short8 pfv = __builtin_bit_cast(short8, fv);
#pragma unroll
      for (int k0 = 0; k0 < 4; ++k0) {
        short8 vf = *(const short8*)&Vts[(k0 << 4) + c][(gp << 3)];
        accO[k0] = __builtin_amdgcn_mfma_f32_16x16x32_bf16(pfv, vf, accO[k0], 0, 0, 0);
      }
    }
  }

  float dr[4];
  dr[0] = __shfl(denom, (gp << 2) + 0);
  dr[1] = __shfl(denom, (gp << 2) + 1);
  dr[2] = __shfl(denom, (gp << 2) + 2);
  dr[3] = __shfl(denom, (gp << 2) + 3);
#pragma unroll
  for (int r = 0; r < 4; ++r) {
    const int grow = qbase + (gp << 2) + r;
    if (grow == L_ - 1) continue;
    const size_t base = ((size_t)((b * L_ + grow) * H_ + h)) * D_ + c;
    const float inv = 1.0f / dr[r];
    Og[base +  0] = accO[0][r] * inv;
    Og[base + 16] = accO[1][r] * inv;
    Og[base + 32] = accO[2][r] * inv;
    Og[base + 48] = accO[3][r] * inv;
  }
}

__global__ __launch_bounds__(256) void vmean_fix(const float* __restrict__ Vg,
                                                 float* __restrict__ Og) {
  const int bh = blockIdx.x;
  const int b = bh >> 4, h = bh & 15;
  const int t = (int)threadIdx.x;
  const int lane = t & 63, w = t >> 6;
  float sum = 0.f;
  for (int s = w; s < S_; s += 4)
    sum += Vg[((size_t)((b * S_ + s) * H_ + h)) * D_ + lane];
  __shared__ float red[4][64];
  red[w][lane] = sum;
  __syncthreads();
  if (w == 0) {
    float tot = red[0][lane] + red[1][lane] + red[2][lane] + red[3][lane];
    Og[((size_t)((b * L_ + (L_ - 1)) * H_ + h)) * D_ + lane] = tot * (1.0f / (float)S_);
  }
}

extern "C" void kernel_launch(void* const* d_in, const int* in_sizes, int n_in,
                              void* d_out, int out_size, void* d_ws, size_t ws_size,
                              hipStream_t stream) {
  const float* Q = (const float*)d_in[0];
  const float* K = (const float*)d_in[1];
  const float* V = (const float*)d_in[2];
  float* O = (float*)d_out;
  const size_t szK = (size_t)B_ * H_ * S_ * E_ * 2;    // 8 MB bf16 K
  const size_t szV = (size_t)B_ * H_ * D_ * S_ * 2;    // 8 MB bf16 V^T
  const size_t szP = (size_t)(B_ * H_ * 32) * 64 * 4;  // 256 KB partials

  if (ws_size >= szK + szV + szP) {
    ushort* Kb = (ushort*)d_ws;
    ushort* Vt = (ushort*)((char*)d_ws + szK);
    float* part = (float*)((char*)d_ws + szK + szV);
    prep_all<<<dim3(3072), dim3(256), 0, stream>>>(K, V, Kb, Vt, part);
    attn_fwd17<<<dim3(B_ * H_, L_ / 128), dim3(256), 0, stream>>>(Q, Kb, Vt, O);
    vmean_comb<<<dim3(B_ * H_), dim3(64), 0, stream>>>(part, O);
  } else {
    attn_fwd<<<dim3(B_ * H_, L_ / 64), dim3(256), 0, stream>>>(Q, K, V, O);
    vmean_fix<<<dim3(B_ * H_), dim3(256), 0, stream>>>(V, O);
  }
}